// Round 8
// baseline (153.592 us; speedup 1.0000x reference)
//
#include <hip/hip_runtime.h>
#include <hip/hip_bf16.h>
#include <stdint.h>

// SimpleVectorQuantizer: vecs [16,32,128,64] f32, codebook [512,64] f32.
// Outputs (flat f32): vecs_hat [65536*64], z [65536] (as float), l_commit, l_codebook.
//
// Round 8: kill the hot-loop scratch spills by SHRINKING per-wave state.
// r7: VGPR_Count=120 vs ~170 demand (4 m-tiles/wave) -> TOP2 state in scratch,
// MfmaUtil 6.7%, 70 us. Now 2 m-tiles/wave (32 vectors), 4 waves/block of 128
// vectors: demand ~110 regs -> spill-free; same total MFMA work across 2x waves.

#define VQ_K 64
#define VQ_S 512
#define NTHREADS 256                     // 4 waves
#define VPB 128                          // vectors per block
#define MT 2                             // m-tiles per wave
#define PHASES 4
#define NT_PER_PHASE 8                   // 8 n-tiles of 16 codewords per phase
#define ROWB 272                         // B row: 64 hi bf16 + 64 lo bf16 + 16 pad
#define PHASE_BYTES (NT_PER_PHASE * 16 * ROWB)   // 34816
#define PHASE_F4 (PHASE_BYTES / 16)      // 2176
#define CSQ_OFF (VQ_S * ROWB)            // 139264
#define CELL 7.62939453125e-6f           // f32 ulp at score magnitude ~64
#define GAP_THRESH (8.0f * CELL)

typedef __attribute__((ext_vector_type(8))) short bf16x8;
typedef __attribute__((ext_vector_type(4))) float f32x4;

static __device__ __forceinline__ unsigned short f2bf_rne(float f) {
    unsigned u = __float_as_uint(f);
    unsigned r = (u + 0x7fffu + ((u >> 16) & 1u)) >> 16;
    return (unsigned short)r;
}
static __device__ __forceinline__ float bf2f(unsigned short h) {
    return __uint_as_float(((unsigned)h) << 16);
}

// K1: one wave per codebook row; lane k handles element k.
__global__ __launch_bounds__(256, 1) void vq_prep(
    const float* __restrict__ cb, unsigned char* __restrict__ bimg) {
    const int lane = threadIdx.x & 63;
    const int row = blockIdx.x * 4 + (threadIdx.x >> 6);
    float c = cb[(size_t)row * VQ_K + lane];
    double d = (double)c * (double)c;
#pragma unroll
    for (int off = 1; off <= 32; off <<= 1) d += __shfl_xor(d, off, 64);
    unsigned short hi = f2bf_rne(c);
    unsigned short lo = f2bf_rne(c - bf2f(hi));
    unsigned char* rowp = bimg + (size_t)row * ROWB;
    ((unsigned short*)rowp)[lane] = hi;
    ((unsigned short*)(rowp + 128))[lane] = lo;
    if (lane == 0) ((float*)(bimg + CSQ_OFF))[row] = (float)d;
}

// K2: MFMA scan + in-block exact rescue. 4 waves x 2 m-tiles = 128 vectors.
__global__ __launch_bounds__(NTHREADS, 2) void vq_mfma(
    const float* __restrict__ vecs, const float* __restrict__ codebook,
    const unsigned char* __restrict__ bimg,
    float* __restrict__ out_hat, float* __restrict__ out_z,
    float* __restrict__ out_loss, float inv_n) {
    __shared__ unsigned char ldsB[PHASE_BYTES];   // 34816 B
    __shared__ float csq_sh[VQ_S];                // 2 KB
    __shared__ float vsq_all[VPB];
    __shared__ int zsh[VPB];
    __shared__ int rlist[VPB];
    __shared__ int rn;

    const int tid = threadIdx.x;
    const int wave = tid >> 6;                    // 0..3
    const int lane = tid & 63;
    const int m = lane & 15;
    const int q = lane >> 4;
    const int blockbase = blockIdx.x * VPB;
    const int wavebase = blockbase + wave * 32;   // 32 vectors per wave

    if (tid == 0) rn = 0;

    // ---- A fragments (bf16 split) + exact vsq ----
    bf16x8 ah1[MT], ah2[MT], al1[MT], al2[MT];
    f32x4 vsqf[MT];
#pragma unroll
    for (int mt = 0; mt < MT; ++mt) {
        const float* vp = vecs + (size_t)(wavebase + mt * 16 + m) * VQ_K + q * 8;
        float4 a0 = ((const float4*)vp)[0];
        float4 a1 = ((const float4*)vp)[1];
        float4 b0 = ((const float4*)(vp + 32))[0];
        float4 b1 = ((const float4*)(vp + 32))[1];
        float w1[8] = {a0.x, a0.y, a0.z, a0.w, a1.x, a1.y, a1.z, a1.w};
        float w2[8] = {b0.x, b0.y, b0.z, b0.w, b1.x, b1.y, b1.z, b1.w};
        double p = 0.0;
#pragma unroll
        for (int j = 0; j < 8; ++j) {
            double d1 = (double)w1[j], d2 = (double)w2[j];
            p = fma(d1, d1, p); p = fma(d2, d2, p);
        }
        p += __shfl_xor(p, 16, 64);
        p += __shfl_xor(p, 32, 64);
        if (q == 0) vsq_all[wave * 32 + mt * 16 + m] = (float)p;
#pragma unroll
        for (int j = 0; j < 8; ++j) {
            unsigned short h1 = f2bf_rne(w1[j]);
            unsigned short h2 = f2bf_rne(w2[j]);
            ah1[mt][j] = (short)h1;
            ah2[mt][j] = (short)h2;
            al1[mt][j] = (short)f2bf_rne(w1[j] - bf2f(h1));
            al2[mt][j] = (short)f2bf_rne(w2[j] - bf2f(h2));
        }
        vsqf[mt] = *(const f32x4*)&vsq_all[wave * 32 + mt * 16 + q * 4];
    }

    // 8 states per lane: st = mt*4 + r
    float t1s[8], t2s[8];
    int t1i[8];
#pragma unroll
    for (int st = 0; st < 8; ++st) { t1s[st] = 3.4e38f; t2s[st] = 3.4e38f; t1i[st] = 0; }
    const f32x4 zero4 = {0.f, 0.f, 0.f, 0.f};
    const unsigned char* ldsrow = ldsB + m * ROWB + q * 16;

    for (int p = 0; p < PHASES; ++p) {
        __syncthreads();
        {
            const float4* src = (const float4*)(bimg + (size_t)p * PHASE_BYTES);
            float4* dst = (float4*)ldsB;
#pragma unroll
            for (int j = 0; j < 9; ++j) {
                int i = tid + j * NTHREADS;
                if (i < PHASE_F4) dst[i] = src[i];
            }
            if (p == 0 && tid < 128)
                ((float4*)csq_sh)[tid] = ((const float4*)(bimg + CSQ_OFF))[tid];
        }
        __syncthreads();

#pragma unroll
        for (int t = 0; t < NT_PER_PHASE; ++t) {
            const int nbase = p * 128 + t * 16;
            const float csqn = csq_sh[nbase + m];
            const int nidx = nbase + m;
            bf16x8 bh1 = *(const bf16x8*)(ldsrow + t * 16 * ROWB);
            bf16x8 bh2 = *(const bf16x8*)(ldsrow + t * 16 * ROWB + 64);
            bf16x8 bl1 = *(const bf16x8*)(ldsrow + t * 16 * ROWB + 128);
            bf16x8 bl2 = *(const bf16x8*)(ldsrow + t * 16 * ROWB + 192);
#pragma unroll
            for (int mt = 0; mt < MT; ++mt) {
                f32x4 acc = __builtin_amdgcn_mfma_f32_16x16x32_bf16(ah1[mt], bh1, zero4, 0, 0, 0);
                acc = __builtin_amdgcn_mfma_f32_16x16x32_bf16(ah2[mt], bh2, acc, 0, 0, 0);
                acc = __builtin_amdgcn_mfma_f32_16x16x32_bf16(ah1[mt], bl1, acc, 0, 0, 0);
                acc = __builtin_amdgcn_mfma_f32_16x16x32_bf16(ah2[mt], bl2, acc, 0, 0, 0);
                acc = __builtin_amdgcn_mfma_f32_16x16x32_bf16(al1[mt], bh1, acc, 0, 0, 0);
                acc = __builtin_amdgcn_mfma_f32_16x16x32_bf16(al2[mt], bh2, acc, 0, 0, 0);
#pragma unroll
                for (int r = 0; r < 4; ++r) {
                    float sc = fmaf(-2.0f, acc[r], vsqf[mt][r]) + csqn;
                    const int st = mt * 4 + r;
                    bool b1 = sc < t1s[st];
                    bool b2 = sc < t2s[st];
                    t2s[st] = b1 ? t1s[st] : (b2 ? sc : t2s[st]);
                    t1s[st] = b1 ? sc : t1s[st];
                    t1i[st] = b1 ? nidx : t1i[st];
                }
            }
        }
    }

    // ---- butterfly merge over the 16 n-columns ----
    unsigned long long pk[8];
#pragma unroll
    for (int st = 0; st < 8; ++st) {
        unsigned u = __float_as_uint(t1s[st]);
        unsigned mono = (u & 0x80000000u) ? ~u : (u | 0x80000000u);
        pk[st] = ((unsigned long long)mono << 32) | (unsigned)t1i[st];
    }
#pragma unroll
    for (int dd = 1; dd <= 8; dd <<= 1) {
#pragma unroll
        for (int st = 0; st < 8; ++st) {
            unsigned long long opk = __shfl_xor(pk[st], dd, 64);
            float o1 = __shfl_xor(t1s[st], dd, 64);
            float o2 = __shfl_xor(t2s[st], dd, 64);
            t2s[st] = fminf(fmaxf(t1s[st], o1), fminf(t2s[st], o2));
            t1s[st] = fminf(t1s[st], o1);
            pk[st] = opk < pk[st] ? opk : pk[st];
        }
    }

    // ---- writers: lanes with m<8 own vector (mt=m>>2, row=q*4+(m&3)) ----
    float w1s = 3.4e38f, w2s = 3.4e38f;
    unsigned long long wpk = 0;
#pragma unroll
    for (int i = 0; i < 8; ++i) {
        bool sel = (m == i);
        w1s = sel ? t1s[i] : w1s;
        w2s = sel ? t2s[i] : w2s;
        wpk = sel ? pk[i] : wpk;
    }
    const bool writer = (m < 8);
    const int vloc = wave * 32 + ((m >> 2) & 1) * 16 + q * 4 + (m & 3);
    if (writer) {
        zsh[vloc] = (int)(wpk & 0xffffffffull);
        if (w2s - w1s <= GAP_THRESH) {
            int pos = atomicAdd(&rn, 1);
            rlist[pos] = vloc;
        }
    }
    float dl = writer ? ((w1s < 0.f ? 0.f : w1s) * inv_n) : 0.f;
#pragma unroll
    for (int off = 32; off >= 1; off >>= 1) dl += __shfl_down(dl, off, 64);
    if (lane == 0) { atomicAdd(&out_loss[0], dl); atomicAdd(&out_loss[1], dl); }

    __syncthreads();

    // ---- in-block exact rescue: wave w handles rlist[i*4+w] ----
    const int nr = rn;
    for (int base = 0; base < nr; base += 4) {
        const int slot = base + wave;
        if (slot < nr) {                       // wave-uniform
            const int rv = rlist[slot];
            const float4* vrow4 = (const float4*)(vecs + (size_t)(blockbase + rv) * VQ_K);
            const float vsqr = vsq_all[rv];
            unsigned long long best = ~0ull;
            for (int j = 0; j < 8; ++j) {
                const int s = lane * 8 + j;
                const float4* crow = (const float4*)(codebook + (size_t)s * VQ_K);
                double acc = 0.0;
#pragma unroll
                for (int qq = 0; qq < VQ_K / 4; ++qq) {
                    float4 c = crow[qq];
                    float4 t = vrow4[qq];      // wave-uniform -> scalar loads
                    acc = fma((double)c.x, (double)t.x, acc);
                    acc = fma((double)c.y, (double)t.y, acc);
                    acc = fma((double)c.z, (double)t.z, acc);
                    acc = fma((double)c.w, (double)t.w, acc);
                }
                float e = (float)acc;
                float sc = fmaf(-2.0f, e, vsqr) + csq_sh[s];
                unsigned u = __float_as_uint(sc);
                unsigned mono = (u & 0x80000000u) ? ~u : (u | 0x80000000u);
                unsigned long long pkr = ((unsigned long long)mono << 32) | (unsigned)s;
                best = pkr < best ? pkr : best;
            }
#pragma unroll
            for (int off = 32; off >= 1; off >>= 1) {
                unsigned long long o = __shfl_down(best, off, 64);
                best = o < best ? o : best;
            }
            if (lane == 0) zsh[rv] = (int)(best & 0xffffffffull);
        }
    }
    __syncthreads();

    // ---- coalesced z write + gather ----
    if (tid < VPB) out_z[blockbase + tid] = (float)zsh[tid];
    const float4* cb4 = (const float4*)codebook;
    float4* hat4 = (float4*)(out_hat + (size_t)blockbase * VQ_K);
    const int F = VPB * (VQ_K / 4);                // 2048
#pragma unroll
    for (int f = tid; f < F; f += NTHREADS) {
        int vv = f >> 4;
        int k4 = f & 15;
        hat4[f] = cb4[zsh[vv] * (VQ_K / 4) + k4];
    }
}

extern "C" void kernel_launch(void* const* d_in, const int* in_sizes, int n_in,
                              void* d_out, int out_size, void* d_ws, size_t ws_size,
                              hipStream_t stream) {
    const float* vecs = (const float*)d_in[0];
    const float* codebook = (const float*)d_in[1];
    float* out = (float*)d_out;

    const int nvec = in_sizes[0] / VQ_K;            // 65536
    unsigned char* bimg = (unsigned char*)d_ws;     // 141312 B image

    float* out_hat = out;
    float* out_z = out + (size_t)nvec * VQ_K;
    float* out_loss = out + out_size - 2;

    hipMemsetAsync(out_loss, 0, 2 * sizeof(float), stream);
    vq_prep<<<VQ_S / 4, 256, 0, stream>>>(codebook, bimg);
    vq_mfma<<<nvec / VPB, NTHREADS, 0, stream>>>(
        vecs, codebook, bimg, out_hat, out_z, out_loss, 1.0f / (float)nvec);
}